// Round 9
// baseline (397.585 us; speedup 1.0000x reference)
//
#include <hip/hip_runtime.h>
#include <math.h>

#define DD 256
#define KK 8192
#define NN 16384
#define DECAYF 0.99f
#define EPSF 1e-5f
#define TAU 4e-3f

// output layout (floats)
#define O_Q    0
#define O_LOSS 4194304
#define O_PERP 4194305
#define O_IDX  4194306
#define O_EMB  4210690

typedef float f32x4 __attribute__((ext_vector_type(4)));
typedef _Float16 f16x8 __attribute__((ext_vector_type(8)));

__device__ __forceinline__ unsigned short f2h(float f) {
  union { _Float16 h; unsigned short u; } c;
  c.h = (_Float16)f;
  return c.u;
}

__device__ __forceinline__ void gll16(const void* g, void* l) {
  __builtin_amdgcn_global_load_lds((const __attribute__((address_space(1))) void*)g,
                                   (__attribute__((address_space(3))) void*)l, 16, 0, 0);
}

// ------- x -> fp16 [N,D]; also zeroes dwT (1 float2/thread) + small scratch --
__global__ void k_convert_x(const float* __restrict__ x, unsigned short* __restrict__ Ah,
                            float* __restrict__ esq, float* __restrict__ dwT,
                            float* __restrict__ counts, float* __restrict__ loss_part,
                            int* __restrict__ listc) {
  int tid = threadIdx.x;
  int i = blockIdx.x * 256 + tid; // float4 index, 1048576 total
  // zero dwT: 1M float2 == 8 MB, exactly one per thread
  ((float2*)dwT)[i] = make_float2(0.f, 0.f);
  if (blockIdx.x < 32) esq[blockIdx.x * 256 + tid] = 0.f;
  else if (blockIdx.x < 64) counts[(blockIdx.x - 32) * 256 + tid] = 0.f;
  else if (blockIdx.x == 64) { loss_part[tid] = 0.f; if (tid == 0) *listc = 0; }
  float4 v = ((const float4*)x)[i];
  ushort4 h;
  h.x = f2h(v.x); h.y = f2h(v.y); h.z = f2h(v.z); h.w = f2h(v.w);
  ((ushort4*)Ah)[i] = h;
}

// ------- transpose emb [D,K] -> embT fp32 [K,D] + Eh fp16 [K,D] + esq -------
__global__ void k_convert_e(const float* __restrict__ emb, unsigned short* __restrict__ Eh,
                            float* __restrict__ embT, float* __restrict__ esq) {
  __shared__ float ld[32 * 33];
  int t = threadIdx.x;
  int k0 = blockIdx.x * 32, d0 = blockIdx.y * 32;
  {
    int din = t >> 3, kq = (t & 7) * 4;
    float4 v = *(const float4*)(emb + (size_t)(d0 + din) * KK + k0 + kq);
    ld[din * 33 + kq + 0] = v.x; ld[din * 33 + kq + 1] = v.y;
    ld[din * 33 + kq + 2] = v.z; ld[din * 33 + kq + 3] = v.w;
  }
  __syncthreads();
  int kout = t >> 3, dq = (t & 7) * 4;
  float f0 = ld[(dq + 0) * 33 + kout], f1 = ld[(dq + 1) * 33 + kout];
  float f2 = ld[(dq + 2) * 33 + kout], f3 = ld[(dq + 3) * 33 + kout];
  size_t o = (size_t)(k0 + kout) * DD + d0 + dq;
  float4 fv; fv.x = f0; fv.y = f1; fv.z = f2; fv.w = f3;
  *(float4*)(embT + o) = fv;
  ushort4 hv;
  hv.x = f2h(f0); hv.y = f2h(f1); hv.z = f2h(f2); hv.w = f2h(f3);
  *(ushort4*)(Eh + o) = hv;
  float p = (f0 * f0 + f1 * f1) + (f2 * f2 + f3 * f3);
  p += __shfl_xor(p, 1, 64);
  p += __shfl_xor(p, 2, 64);
  p += __shfl_xor(p, 4, 64);
  if ((t & 7) == 0) atomicAdd(esq + k0 + kout, p);
}

// ---------------- MFMA distance screening (fp16 single GEMM) ----------------
// grid (64 kb, 128 nb); 256 threads = 4 waves; tile 128x128; BD=64 per iter.
// launch_bounds(256,4): 4 blocks/CU so barrier drains overlap across blocks.
__launch_bounds__(256, 4)
__global__ void k_dist_mfma(const unsigned short* __restrict__ Ah, const unsigned short* __restrict__ Bh,
                            const float* __restrict__ esq,
                            float* __restrict__ part1, float* __restrict__ part2,
                            int* __restrict__ partidx) {
  __shared__ __align__(16) unsigned short sA[8192]; // 128 rows x 64 f16 (16 KB)
  __shared__ __align__(16) unsigned short sB[8192];

  const int tid = threadIdx.x;
  const int w = tid >> 6, lane = tid & 63;
  const int kb = blockIdx.x, nb = blockIdx.y;
  const int row0 = nb * 128, col0 = kb * 128;

  size_t gA[4], gB[4];
  int lbase[4];
  #pragma unroll
  for (int s = 0; s < 4; ++s) {
    int r = (w * 4 + s) * 8 + (lane >> 3);
    int c = (lane & 7) ^ (r & 7);
    gA[s] = (size_t)(row0 + r) * DD + c * 8;
    gB[s] = (size_t)(col0 + r) * DD + c * 8;
    lbase[s] = (w * 4 + s) * 512;
  }
  const int m = lane & 15, q = lane >> 4;

  f32x4 acc[2][8];
  #pragma unroll
  for (int i = 0; i < 2; ++i)
    #pragma unroll
    for (int j = 0; j < 8; ++j) acc[i][j] = (f32x4)0.f;

  for (int it = 0; it < 4; ++it) {
    const int d0 = it * 64;
    __syncthreads();
    #pragma unroll
    for (int s = 0; s < 4; ++s) {
      gll16(Ah + gA[s] + d0, sA + lbase[s]);
      gll16(Bh + gB[s] + d0, sB + lbase[s]);
    }
    __syncthreads();
    #pragma unroll
    for (int kk = 0; kk < 2; ++kk) {
      f16x8 a[2];
      #pragma unroll
      for (int i = 0; i < 2; ++i) {
        int wr = w * 32 + i * 16 + m;
        int slot = (kk * 4 + q) ^ (wr & 7);
        a[i] = *(const f16x8*)(sA + wr * 64 + slot * 8);
      }
      #pragma unroll
      for (int j = 0; j < 8; ++j) {
        int cn = j * 16 + m;
        int slot = (kk * 4 + q) ^ (cn & 7);
        f16x8 b = *(const f16x8*)(sB + cn * 64 + slot * 8);
        acc[0][j] = __builtin_amdgcn_mfma_f32_16x16x32_f16(a[0], b, acc[0][j], 0, 0, 0);
        acc[1][j] = __builtin_amdgcn_mfma_f32_16x16x32_f16(a[1], b, acc[1][j], 0, 0, 0);
      }
    }
  }

  float eq[8];
  #pragma unroll
  for (int j = 0; j < 8; ++j) eq[j] = esq[col0 + j * 16 + m];

  #pragma unroll
  for (int i = 0; i < 2; ++i) {
    #pragma unroll
    for (int reg = 0; reg < 4; ++reg) {
      float m1 = 3.402823466e+38f, m2 = 3.402823466e+38f;
      int bi = 0;
      #pragma unroll
      for (int j = 0; j < 8; ++j) {
        float dd = fmaf(-2.0f, acc[i][j][reg], eq[j]);
        if (dd < m1) { m2 = m1; m1 = dd; bi = col0 + j * 16 + m; }
        else if (dd < m2) m2 = dd;
      }
      #pragma unroll
      for (int st = 1; st < 16; st <<= 1) {
        float ov = __shfl_xor(m1, st, 64);
        int   oi = __shfl_xor(bi, st, 64);
        float o2 = __shfl_xor(m2, st, 64);
        float big = fmaxf(m1, ov);
        m2 = fminf(fminf(m2, o2), big);
        if (ov < m1 || (ov == m1 && oi < bi)) { m1 = ov; bi = oi; }
      }
      if (m == 0) {
        int prow = row0 + w * 32 + i * 16 + q * 4 + reg;
        int pidx = prow * 64 + kb;
        part1[pidx] = m1; part2[pidx] = m2; partidx[pidx] = bi;
      }
    }
  }
}

// ------- reduce 64 k-block partials per row; also init keys[row] = ~0 -------
__global__ void k_argmin2(const float* __restrict__ part1, const float* __restrict__ part2,
                          const int* __restrict__ partidx, int* __restrict__ idxw,
                          int* __restrict__ listc, int* __restrict__ list,
                          unsigned long long* __restrict__ keys) {
  int w = threadIdx.x >> 6, l = threadIdx.x & 63;
  int row = blockIdx.x * 4 + w;
  int base = row * 64 + l;
  float m1 = part1[base], m2 = part2[base];
  int bi = partidx[base];
  #pragma unroll
  for (int st = 1; st < 64; st <<= 1) {
    float ov = __shfl_xor(m1, st, 64);
    int   oi = __shfl_xor(bi, st, 64);
    float o2 = __shfl_xor(m2, st, 64);
    float big = fmaxf(m1, ov);
    m2 = fminf(fminf(m2, o2), big);
    if (ov < m1 || (ov == m1 && oi < bi)) { m1 = ov; bi = oi; }
  }
  if (l == 0) {
    idxw[row] = bi;
    keys[row] = ~0ull;
    if (m2 - m1 < TAU) { int pos = atomicAdd(listc, 1); list[pos] = row; }
  }
}

// ---------------- fp64 rescore of near-tie rows (parallel over rows) --------
__global__ void k_rescore(const float* __restrict__ x, const float* __restrict__ emb,
                          const int* __restrict__ listc, const int* __restrict__ list,
                          unsigned long long* __restrict__ keys) {
  __shared__ float se[8192];
  __shared__ double red[256];
  const int t = threadIdx.x;
  const int k0 = blockIdx.x * 32;
  #pragma unroll
  for (int i = 0; i < 32; ++i) {
    int elem = i * 256 + t;
    int d = elem >> 5, c = elem & 31;
    se[d * 32 + c] = emb[(size_t)d * KK + k0 + c];
  }
  __syncthreads();
  const int c = t & 31, p = t >> 5;
  int cnt = *listc;
  for (int li = blockIdx.y; li < cnt; li += gridDim.y) {
    int row = list[li];
    const float* xr = x + (size_t)row * DD;
    double acc = 0.0;
    #pragma unroll
    for (int j = 0; j < 32; ++j) {
      int d = p * 32 + j;
      double df = (double)xr[d] - (double)se[d * 32 + c];
      acc = fma(df, df, acc);
    }
    red[c * 8 + p] = acc;
    __syncthreads();
    if (t < 64) {
      unsigned long long key = ~0ull;
      if (t < 32) {
        double dist = 0.0;
        #pragma unroll
        for (int qq = 0; qq < 8; ++qq) dist += red[t * 8 + qq];
        key = ((unsigned long long)__double_as_longlong(dist) & ~0x1FFFull)
              | (unsigned long long)(k0 + t);
      }
      #pragma unroll
      for (int s = 1; s < 64; s <<= 1) {
        unsigned long long o = __shfl_xor(key, s, 64);
        if (o < key) key = o;
      }
      if (t == 0) atomicMin(&keys[row], key);
    }
    __syncthreads();
  }
}

// ---------------- gather + outputs + scatter stats ----------------
__global__ void k_gather(const float* __restrict__ x, const float* __restrict__ embT,
                         const int* __restrict__ idxw, const unsigned long long* __restrict__ keys,
                         const int* __restrict__ train,
                         float* __restrict__ outq, float* __restrict__ outidx,
                         float* __restrict__ dwT, float* __restrict__ counts,
                         float* __restrict__ loss_part) {
  int w = threadIdx.x >> 6, l = threadIdx.x & 63;
  int n = blockIdx.x * 4 + w;
  unsigned long long kv = keys[n];
  int k = (kv != ~0ull) ? (int)(kv & 0x1FFFull) : idxw[n];
  float4 xv = ((const float4*)(x + (size_t)n * DD))[l];
  float4 qv = ((const float4*)(embT + (size_t)k * DD))[l];
  int d = l * 4;

  ((float4*)(outq + (size_t)n * DD))[l] = qv; // x + (q - x) == q

  float e0 = qv.x - xv.x, e1 = qv.y - xv.y, e2 = qv.z - xv.z, e3 = qv.w - xv.w;
  float ls = (e0 * e0 + e1 * e1) + (e2 * e2 + e3 * e3);

  if (*train) {
    const float wdw = 1.0f - DECAYF;
    float* base = dwT + (size_t)k * DD + d;
    atomicAdd(base + 0, xv.x * wdw);
    atomicAdd(base + 1, xv.y * wdw);
    atomicAdd(base + 2, xv.z * wdw);
    atomicAdd(base + 3, xv.w * wdw);
  }

  #pragma unroll
  for (int s = 1; s < 64; s <<= 1) ls += __shfl_xor(ls, s, 64);
  if (l == 0) {
    atomicAdd(&loss_part[blockIdx.x & 255], ls);
    atomicAdd(&counts[k], 1.0f);
    outidx[n] = (float)k;
  }
}

// ---------------- EMA cluster stats, loss, perplexity ----------------
__global__ void k_stats(const float* __restrict__ counts, const float* __restrict__ ema_cs,
                        const int* __restrict__ counter, const int* __restrict__ train,
                        const float* __restrict__ loss_part, float* __restrict__ csn,
                        float* __restrict__ outloss, float* __restrict__ outperp) {
  __shared__ float s_n[4], s_e[4], s_l[4], s_tot[1];
  int tid = threadIdx.x;
  float debias = 1.0f - powf(DECAYF, (float)(*counter + 1));
  float nloc = 0.f, eloc = 0.f;
  float lloc = loss_part[tid];
  float avg[32];
  for (int i = 0; i < 32; ++i) {
    int k = tid + i * 256;
    float c = counts[k];
    float h = ema_cs[k] * DECAYF + c * (1.0f - DECAYF);
    float a = h / debias;
    avg[i] = a;
    nloc += a;
    float p = c * (1.0f / 16384.0f);
    eloc += p * logf(p + 1e-10f);
  }
  #pragma unroll
  for (int s = 1; s < 64; s <<= 1) {
    nloc += __shfl_xor(nloc, s, 64);
    eloc += __shfl_xor(eloc, s, 64);
    lloc += __shfl_xor(lloc, s, 64);
  }
  int w = tid >> 6, lane = tid & 63;
  if (lane == 0) { s_n[w] = nloc; s_e[w] = eloc; s_l[w] = lloc; }
  __syncthreads();
  if (tid == 0) {
    float nt = (s_n[0] + s_n[1]) + (s_n[2] + s_n[3]);
    float et = (s_e[0] + s_e[1]) + (s_e[2] + s_e[3]);
    float lt = (s_l[0] + s_l[1]) + (s_l[2] + s_l[3]);
    s_tot[0] = nt;
    outperp[0] = expf(-et);
    outloss[0] = 0.25f * (lt / 4194304.0f);
  }
  __syncthreads();
  float nsum = s_tot[0];
  float denom = nsum + 8192.0f * EPSF;
  for (int i = 0; i < 32; ++i) {
    int k = tid + i * 256;
    csn[k] = (avg[i] + EPSF) / denom * nsum;
  }
}

// ---------------- finalize: transpose dwT + EMA + scale -> out4 [D,K] -------
__global__ void k_final(const float* __restrict__ dwT, const float* __restrict__ ema_dw,
                        const float* __restrict__ emb, const float* __restrict__ csn,
                        const int* __restrict__ counter, const int* __restrict__ train,
                        float* __restrict__ out4) {
  __shared__ float ld[32 * 33];
  int t = threadIdx.x;
  int k0 = blockIdx.x * 32, d0 = blockIdx.y * 32;
  if (*train) {
    {
      int ki = t >> 3, dq = (t & 7) * 4;
      float4 v = *(const float4*)(dwT + (size_t)(k0 + ki) * DD + d0 + dq);
      ld[ki * 33 + dq + 0] = v.x; ld[ki * 33 + dq + 1] = v.y;
      ld[ki * 33 + dq + 2] = v.z; ld[ki * 33 + dq + 3] = v.w;
    }
    __syncthreads();
    int dout = t >> 3, kq = (t & 7) * 4;
    size_t o = (size_t)(d0 + dout) * KK + k0 + kq;
    float4 e = *(const float4*)(ema_dw + o);
    float4 c = *(const float4*)(csn + k0 + kq);
    float inv = 1.0f / (1.0f - powf(DECAYF, (float)(*counter + 1)));
    float4 r;
    r.x = fmaf(e.x, DECAYF, ld[(kq + 0) * 33 + dout]) * inv / c.x;
    r.y = fmaf(e.y, DECAYF, ld[(kq + 1) * 33 + dout]) * inv / c.y;
    r.z = fmaf(e.z, DECAYF, ld[(kq + 2) * 33 + dout]) * inv / c.z;
    r.w = fmaf(e.w, DECAYF, ld[(kq + 3) * 33 + dout]) * inv / c.w;
    *(float4*)(out4 + o) = r;
  } else {
    int dout = t >> 3, kq = (t & 7) * 4;
    size_t o = (size_t)(d0 + dout) * KK + k0 + kq;
    *(float4*)(out4 + o) = *(const float4*)(emb + o);
  }
}

extern "C" void kernel_launch(void* const* d_in, const int* in_sizes, int n_in,
                              void* d_out, int out_size, void* d_ws, size_t ws_size,
                              hipStream_t stream) {
  (void)in_sizes; (void)n_in; (void)out_size; (void)ws_size;
  const float* x      = (const float*)d_in[0];
  const float* emb    = (const float*)d_in[1];
  const float* ema_cs = (const float*)d_in[2];
  const float* ema_dw = (const float*)d_in[3];
  const int*   counter = (const int*)d_in[4];
  const int*   train   = (const int*)d_in[5];

  float* out = (float*)d_out;
  float* outq    = out + O_Q;
  float* outloss = out + O_LOSS;
  float* outperp = out + O_PERP;
  float* outidx  = out + O_IDX;
  float* out4    = out + O_EMB;

  // workspace carve (bytes)
  char* W = (char*)d_ws;
  unsigned short* Ah   = (unsigned short*)(W);              //  8 MB fp16 x
  unsigned short* Eh   = (unsigned short*)(W + 8388608);    //  4 MB fp16 embT
  float* embT          = (float*)(W + 12582912);            //  8 MB fp32 embT
  float* part1         = (float*)(W + 20971520);            //  4 MB
  float* part2         = (float*)(W + 25165824);            //  4 MB
  int*   partidx       = (int*)(W + 29360128);              //  4 MB
  float* dwT           = (float*)(W + 33554432);            //  8 MB (dedicated)
  unsigned long long* keys = (unsigned long long*)(W + 41943040); // 128 KB
  float* esq           = (float*)(W + 42074112);            // 32 KB
  float* csn           = (float*)(W + 42106880);            // 32 KB
  float* counts        = (float*)(W + 42139648);            // 32 KB
  float* loss_part     = (float*)(W + 42172416);            // 1 KB
  int*   listc         = (int*)(W + 42173440);
  int*   list          = (int*)(W + 42173444);              // 64 KB
  int*   idxw          = (int*)(W + 42238980);              // 64 KB

  k_convert_x<<<4096, 256, 0, stream>>>(x, Ah, esq, dwT, counts, loss_part, listc);
  k_convert_e<<<dim3(256, 8), 256, 0, stream>>>(emb, Eh, embT, esq);
  k_dist_mfma<<<dim3(64, 128), 256, 0, stream>>>(Ah, Eh, esq, part1, part2, partidx);
  k_argmin2<<<4096, 256, 0, stream>>>(part1, part2, partidx, idxw, listc, list, keys);
  k_rescore<<<dim3(256, 8), 256, 0, stream>>>(x, emb, listc, list, keys);
  k_gather<<<4096, 256, 0, stream>>>(x, embT, idxw, keys, train, outq, outidx, dwT, counts, loss_part);
  k_stats<<<1, 256, 0, stream>>>(counts, ema_cs, counter, train, loss_part, csn, outloss, outperp);
  k_final<<<dim3(256, 8), 256, 0, stream>>>(dwT, ema_dw, emb, csn, counter, train, out4);
}

// Round 10
// 394.513 us; speedup vs baseline: 1.0078x; 1.0078x over previous
//
#include <hip/hip_runtime.h>
#include <math.h>

#define DD 256
#define KK 8192
#define NN 16384
#define DECAYF 0.99f
#define EPSF 1e-5f
#define TAU 4e-3f

// output layout (floats)
#define O_Q    0
#define O_LOSS 4194304
#define O_PERP 4194305
#define O_IDX  4194306
#define O_EMB  4210690

typedef float f32x4 __attribute__((ext_vector_type(4)));
typedef _Float16 f16x8 __attribute__((ext_vector_type(8)));

__device__ __forceinline__ unsigned short f2h(float f) {
  union { _Float16 h; unsigned short u; } c;
  c.h = (_Float16)f;
  return c.u;
}

__device__ __forceinline__ void gll16(const void* g, void* l) {
  __builtin_amdgcn_global_load_lds((const __attribute__((address_space(1))) void*)g,
                                   (__attribute__((address_space(3))) void*)l, 16, 0, 0);
}

// ------- x -> fp16 [N,D]; also zeroes esq/counts/loss_part/listc -----------
__global__ void k_convert_x(const float* __restrict__ x, unsigned short* __restrict__ Ah,
                            float* __restrict__ esq, float* __restrict__ counts,
                            float* __restrict__ loss_part, int* __restrict__ listc) {
  int tid = threadIdx.x;
  int i = blockIdx.x * 256 + tid; // float4 index, 1048576 total
  if (blockIdx.x < 32) esq[blockIdx.x * 256 + tid] = 0.f;
  else if (blockIdx.x < 64) counts[(blockIdx.x - 32) * 256 + tid] = 0.f;
  else if (blockIdx.x == 64) { loss_part[tid] = 0.f; if (tid == 0) *listc = 0; }
  float4 v = ((const float4*)x)[i];
  ushort4 h;
  h.x = f2h(v.x); h.y = f2h(v.y); h.z = f2h(v.z); h.w = f2h(v.w);
  ((ushort4*)Ah)[i] = h;
}

// ------- transpose emb [D,K] -> embT fp32 [K,D] + Eh fp16 [K,D] + esq -------
__global__ void k_convert_e(const float* __restrict__ emb, unsigned short* __restrict__ Eh,
                            float* __restrict__ embT, float* __restrict__ esq) {
  __shared__ float ld[32 * 33];
  int t = threadIdx.x;
  int k0 = blockIdx.x * 32, d0 = blockIdx.y * 32;
  {
    int din = t >> 3, kq = (t & 7) * 4;
    float4 v = *(const float4*)(emb + (size_t)(d0 + din) * KK + k0 + kq);
    ld[din * 33 + kq + 0] = v.x; ld[din * 33 + kq + 1] = v.y;
    ld[din * 33 + kq + 2] = v.z; ld[din * 33 + kq + 3] = v.w;
  }
  __syncthreads();
  int kout = t >> 3, dq = (t & 7) * 4;
  float f0 = ld[(dq + 0) * 33 + kout], f1 = ld[(dq + 1) * 33 + kout];
  float f2 = ld[(dq + 2) * 33 + kout], f3 = ld[(dq + 3) * 33 + kout];
  size_t o = (size_t)(k0 + kout) * DD + d0 + dq;
  float4 fv; fv.x = f0; fv.y = f1; fv.z = f2; fv.w = f3;
  *(float4*)(embT + o) = fv;
  ushort4 hv;
  hv.x = f2h(f0); hv.y = f2h(f1); hv.z = f2h(f2); hv.w = f2h(f3);
  *(ushort4*)(Eh + o) = hv;
  float p = (f0 * f0 + f1 * f1) + (f2 * f2 + f3 * f3);
  p += __shfl_xor(p, 1, 64);
  p += __shfl_xor(p, 2, 64);
  p += __shfl_xor(p, 4, 64);
  if ((t & 7) == 0) atomicAdd(esq + k0 + kout, p);
}

// ---------------- MFMA distance screening (fp16 single GEMM) ----------------
// grid (64 kb, 64 nb); 256 threads = 4 waves; tile 256 rows x 128 cols; BD=64.
// Wave tile 64x128 (acc[4][8]): MFMA:ds_read = 2.67:1 (was 1.6:1, LDS-bound).
__launch_bounds__(256, 2)
__global__ void k_dist_mfma(const unsigned short* __restrict__ Ah, const unsigned short* __restrict__ Bh,
                            const float* __restrict__ esq,
                            float* __restrict__ part1, float* __restrict__ part2,
                            int* __restrict__ partidx) {
  __shared__ __align__(16) unsigned short sA[256 * 64]; // 32 KB
  __shared__ __align__(16) unsigned short sB[128 * 64]; // 16 KB

  const int tid = threadIdx.x;
  const int w = tid >> 6, lane = tid & 63;
  const int kb = blockIdx.x, nb = blockIdx.y;
  const int row0 = nb * 256, col0 = kb * 128;

  // staging: call s covers 32 rows; per-wave dest is contiguous (base+lane*16).
  // LDS slot (lane&7) holds global chunk c = (lane&7)^(r&7).
  size_t gA[8]; int lA[8];
  #pragma unroll
  for (int s = 0; s < 8; ++s) {
    int r = s * 32 + w * 8 + (lane >> 3);
    int c = (lane & 7) ^ (r & 7);
    gA[s] = (size_t)(row0 + r) * DD + c * 8;
    lA[s] = r * 64 + (lane & 7) * 8;
  }
  size_t gB[4]; int lB[4];
  #pragma unroll
  for (int s = 0; s < 4; ++s) {
    int r = s * 32 + w * 8 + (lane >> 3);
    int c = (lane & 7) ^ (r & 7);
    gB[s] = (size_t)(col0 + r) * DD + c * 8;
    lB[s] = r * 64 + (lane & 7) * 8;
  }
  const int m = lane & 15, q = lane >> 4;

  f32x4 acc[4][8];
  #pragma unroll
  for (int i = 0; i < 4; ++i)
    #pragma unroll
    for (int j = 0; j < 8; ++j) acc[i][j] = (f32x4)0.f;

  for (int it = 0; it < 4; ++it) {
    const int d0 = it * 64;
    __syncthreads();
    #pragma unroll
    for (int s = 0; s < 8; ++s) gll16(Ah + gA[s] + d0, sA + lA[s]);
    #pragma unroll
    for (int s = 0; s < 4; ++s) gll16(Bh + gB[s] + d0, sB + lB[s]);
    __syncthreads();
    #pragma unroll
    for (int kk = 0; kk < 2; ++kk) {
      const int kc = kk * 4 + q;
      f16x8 a[4];
      #pragma unroll
      for (int i = 0; i < 4; ++i) {
        int wr = w * 64 + i * 16 + m;
        a[i] = *(const f16x8*)(sA + wr * 64 + (kc ^ (wr & 7)) * 8);
      }
      #pragma unroll
      for (int j = 0; j < 8; ++j) {
        int cn = j * 16 + m;
        f16x8 b = *(const f16x8*)(sB + cn * 64 + (kc ^ (cn & 7)) * 8);
        #pragma unroll
        for (int i = 0; i < 4; ++i)
          acc[i][j] = __builtin_amdgcn_mfma_f32_16x16x32_f16(a[i], b, acc[i][j], 0, 0, 0);
      }
    }
  }

  float eq[8];
  #pragma unroll
  for (int j = 0; j < 8; ++j) eq[j] = esq[col0 + j * 16 + m];

  #pragma unroll
  for (int i = 0; i < 4; ++i) {
    #pragma unroll
    for (int reg = 0; reg < 4; ++reg) {
      float m1 = 3.402823466e+38f, m2 = 3.402823466e+38f;
      int bi = 0;
      #pragma unroll
      for (int j = 0; j < 8; ++j) {
        float dd = fmaf(-2.0f, acc[i][j][reg], eq[j]);
        if (dd < m1) { m2 = m1; m1 = dd; bi = col0 + j * 16 + m; }
        else if (dd < m2) m2 = dd;
      }
      #pragma unroll
      for (int st = 1; st < 16; st <<= 1) {
        float ov = __shfl_xor(m1, st, 64);
        int   oi = __shfl_xor(bi, st, 64);
        float o2 = __shfl_xor(m2, st, 64);
        float big = fmaxf(m1, ov);
        m2 = fminf(fminf(m2, o2), big);
        if (ov < m1 || (ov == m1 && oi < bi)) { m1 = ov; bi = oi; }
      }
      if (m == 0) {
        int prow = row0 + w * 64 + i * 16 + q * 4 + reg;
        int pidx = prow * 64 + kb;
        part1[pidx] = m1; part2[pidx] = m2; partidx[pidx] = bi;
      }
    }
  }
}

// ------- reduce 64 k-block partials per row; also init keys[row] = ~0 -------
__global__ void k_argmin2(const float* __restrict__ part1, const float* __restrict__ part2,
                          const int* __restrict__ partidx, int* __restrict__ idxw,
                          int* __restrict__ listc, int* __restrict__ list,
                          unsigned long long* __restrict__ keys) {
  int w = threadIdx.x >> 6, l = threadIdx.x & 63;
  int row = blockIdx.x * 4 + w;
  int base = row * 64 + l;
  float m1 = part1[base], m2 = part2[base];
  int bi = partidx[base];
  #pragma unroll
  for (int st = 1; st < 64; st <<= 1) {
    float ov = __shfl_xor(m1, st, 64);
    int   oi = __shfl_xor(bi, st, 64);
    float o2 = __shfl_xor(m2, st, 64);
    float big = fmaxf(m1, ov);
    m2 = fminf(fminf(m2, o2), big);
    if (ov < m1 || (ov == m1 && oi < bi)) { m1 = ov; bi = oi; }
  }
  if (l == 0) {
    idxw[row] = bi;
    keys[row] = ~0ull;
    if (m2 - m1 < TAU) { int pos = atomicAdd(listc, 1); list[pos] = row; }
  }
}

// ---------------- fp64 rescore of near-tie rows (parallel over rows) --------
__global__ void k_rescore(const float* __restrict__ x, const float* __restrict__ emb,
                          const int* __restrict__ listc, const int* __restrict__ list,
                          unsigned long long* __restrict__ keys) {
  __shared__ float se[8192];
  __shared__ double red[256];
  const int t = threadIdx.x;
  const int k0 = blockIdx.x * 32;
  #pragma unroll
  for (int i = 0; i < 32; ++i) {
    int elem = i * 256 + t;
    int d = elem >> 5, c = elem & 31;
    se[d * 32 + c] = emb[(size_t)d * KK + k0 + c];
  }
  __syncthreads();
  const int c = t & 31, p = t >> 5;
  int cnt = *listc;
  for (int li = blockIdx.y; li < cnt; li += gridDim.y) {
    int row = list[li];
    const float* xr = x + (size_t)row * DD;
    double acc = 0.0;
    #pragma unroll
    for (int j = 0; j < 32; ++j) {
      int d = p * 32 + j;
      double df = (double)xr[d] - (double)se[d * 32 + c];
      acc = fma(df, df, acc);
    }
    red[c * 8 + p] = acc;
    __syncthreads();
    if (t < 64) {
      unsigned long long key = ~0ull;
      if (t < 32) {
        double dist = 0.0;
        #pragma unroll
        for (int qq = 0; qq < 8; ++qq) dist += red[t * 8 + qq];
        key = ((unsigned long long)__double_as_longlong(dist) & ~0x1FFFull)
              | (unsigned long long)(k0 + t);
      }
      #pragma unroll
      for (int s = 1; s < 64; s <<= 1) {
        unsigned long long o = __shfl_xor(key, s, 64);
        if (o < key) key = o;
      }
      if (t == 0) atomicMin(&keys[row], key);
    }
    __syncthreads();
  }
}

// ------- resolve final index per row + histogram ----------------------------
__global__ void k_index(int* __restrict__ idxw, const unsigned long long* __restrict__ keys,
                        float* __restrict__ counts) {
  int n = blockIdx.x * 256 + threadIdx.x;
  unsigned long long kv = keys[n];
  int k = (kv != ~0ull) ? (int)(kv & 0x1FFFull) : idxw[n];
  idxw[n] = k;
  atomicAdd(&counts[k], 1.0f);
}

// ------- single block: prefix-sum counts -> base/cursor; csn; perplexity ----
__global__ void k_prefix(const float* __restrict__ counts, const float* __restrict__ ema_cs,
                         const int* __restrict__ counter,
                         float* __restrict__ csn, float* __restrict__ outperp,
                         int* __restrict__ base, int* __restrict__ cursor) {
  __shared__ int s_sum[4], s_woff[4];
  __shared__ float s_n[4], s_e[4], s_nsum;
  int t = threadIdx.x, w = t >> 6, lane = t & 63;
  float debias = 1.0f - powf(DECAYF, (float)(*counter + 1));
  int pre[32]; int run = 0; float nloc = 0.f, eloc = 0.f;
  for (int i = 0; i < 32; ++i) {
    int k = t * 32 + i;
    float c = counts[k];
    run += (int)c; pre[i] = run;
    nloc += (ema_cs[k] * DECAYF + c * (1.0f - DECAYF)) / debias;
    float p = c * (1.0f / 16384.0f);
    eloc += p * logf(p + 1e-10f);
  }
  // wave inclusive scan of run
  int inc = run;
  #pragma unroll
  for (int d = 1; d < 64; d <<= 1) {
    int v = __shfl(inc, lane - d, 64);
    if (lane >= d) inc += v;
  }
  int excl = inc - run;
  int wtot = __shfl(inc, 63, 64);
  float ns = nloc, es = eloc;
  #pragma unroll
  for (int d = 1; d < 64; d <<= 1) { ns += __shfl_xor(ns, d, 64); es += __shfl_xor(es, d, 64); }
  if (lane == 0) { s_sum[w] = wtot; s_n[w] = ns; s_e[w] = es; }
  __syncthreads();
  if (t == 0) {
    int off = 0;
    #pragma unroll
    for (int ww = 0; ww < 4; ++ww) { s_woff[ww] = off; off += s_sum[ww]; }
    float nt = (s_n[0] + s_n[1]) + (s_n[2] + s_n[3]);
    float et = (s_e[0] + s_e[1]) + (s_e[2] + s_e[3]);
    s_nsum = nt;
    outperp[0] = expf(-et);
  }
  __syncthreads();
  int tbase = s_woff[w] + excl;
  float nsum = s_nsum;
  float denom = nsum + 8192.0f * EPSF;
  for (int i = 0; i < 32; ++i) {
    int k = t * 32 + i;
    float c = counts[k];
    int b = tbase + pre[i] - (int)c;
    base[k] = b; cursor[k] = b;
    float a = (ema_cs[k] * DECAYF + c * (1.0f - DECAYF)) / debias;
    csn[k] = (a + EPSF) / denom * nsum;
  }
}

// ------- gather: outq/outidx/loss + scatter row into code bucket ------------
__global__ void k_gather(const float* __restrict__ x, const float* __restrict__ embT,
                         const int* __restrict__ idxw, const int* __restrict__ train,
                         float* __restrict__ outq, float* __restrict__ outidx,
                         int* __restrict__ rowlist, int* __restrict__ cursor,
                         float* __restrict__ loss_part) {
  int w = threadIdx.x >> 6, l = threadIdx.x & 63;
  int n = blockIdx.x * 4 + w;
  int k = idxw[n];
  float4 xv = ((const float4*)(x + (size_t)n * DD))[l];
  float4 qv = ((const float4*)(embT + (size_t)k * DD))[l];

  ((float4*)(outq + (size_t)n * DD))[l] = qv; // x + (q - x) == q

  float e0 = qv.x - xv.x, e1 = qv.y - xv.y, e2 = qv.z - xv.z, e3 = qv.w - xv.w;
  float ls = (e0 * e0 + e1 * e1) + (e2 * e2 + e3 * e3);
  #pragma unroll
  for (int s = 1; s < 64; s <<= 1) ls += __shfl_xor(ls, s, 64);
  if (l == 0) {
    atomicAdd(&loss_part[blockIdx.x & 255], ls);
    outidx[n] = (float)k;
    if (*train) {
      int pos = atomicAdd(&cursor[k], 1);
      rowlist[pos] = n;
    }
  }
}

// ------- dw segmented reduction: block per code, no atomics -----------------
__global__ void k_dw(const float* __restrict__ x, const int* __restrict__ base,
                     const float* __restrict__ counts, const int* __restrict__ rowlist,
                     const int* __restrict__ train, float* __restrict__ dwT) {
  if (!*train) return;
  int c = blockIdx.x, l = threadIdx.x; // 64 threads
  int b0 = base[c], cnt = (int)counts[c];
  float4 acc = make_float4(0.f, 0.f, 0.f, 0.f);
  for (int i = 0; i < cnt; ++i) {
    int row = rowlist[b0 + i];
    float4 v = ((const float4*)(x + (size_t)row * DD))[l];
    acc.x += v.x; acc.y += v.y; acc.z += v.z; acc.w += v.w;
  }
  const float wdw = 1.0f - DECAYF;
  acc.x *= wdw; acc.y *= wdw; acc.z *= wdw; acc.w *= wdw;
  ((float4*)(dwT + (size_t)c * DD))[l] = acc;
}

// ------- finalize: transpose dwT + EMA + scale -> out4 [D,K]; loss ----------
__global__ void k_final(const float* __restrict__ dwT, const float* __restrict__ ema_dw,
                        const float* __restrict__ emb, const float* __restrict__ csn,
                        const int* __restrict__ counter, const int* __restrict__ train,
                        const float* __restrict__ loss_part, float* __restrict__ outloss,
                        float* __restrict__ out4) {
  __shared__ float ld[32 * 33];
  __shared__ float sl[4];
  int t = threadIdx.x;
  if (blockIdx.x == 0 && blockIdx.y == 0) {
    float ll = loss_part[t];
    #pragma unroll
    for (int d = 1; d < 64; d <<= 1) ll += __shfl_xor(ll, d, 64);
    if ((t & 63) == 0) sl[t >> 6] = ll;
    __syncthreads();
    if (t == 0) outloss[0] = 0.25f * (((sl[0] + sl[1]) + (sl[2] + sl[3])) / 4194304.0f);
  }
  int k0 = blockIdx.x * 32, d0 = blockIdx.y * 32;
  if (*train) {
    {
      int ki = t >> 3, dq = (t & 7) * 4;
      float4 v = *(const float4*)(dwT + (size_t)(k0 + ki) * DD + d0 + dq);
      ld[ki * 33 + dq + 0] = v.x; ld[ki * 33 + dq + 1] = v.y;
      ld[ki * 33 + dq + 2] = v.z; ld[ki * 33 + dq + 3] = v.w;
    }
    __syncthreads();
    int dout = t >> 3, kq = (t & 7) * 4;
    size_t o = (size_t)(d0 + dout) * KK + k0 + kq;
    float4 e = *(const float4*)(ema_dw + o);
    float4 c = *(const float4*)(csn + k0 + kq);
    float inv = 1.0f / (1.0f - powf(DECAYF, (float)(*counter + 1)));
    float4 r;
    r.x = fmaf(e.x, DECAYF, ld[(kq + 0) * 33 + dout]) * inv / c.x;
    r.y = fmaf(e.y, DECAYF, ld[(kq + 1) * 33 + dout]) * inv / c.y;
    r.z = fmaf(e.z, DECAYF, ld[(kq + 2) * 33 + dout]) * inv / c.z;
    r.w = fmaf(e.w, DECAYF, ld[(kq + 3) * 33 + dout]) * inv / c.w;
    *(float4*)(out4 + o) = r;
  } else {
    int dout = t >> 3, kq = (t & 7) * 4;
    size_t o = (size_t)(d0 + dout) * KK + k0 + kq;
    *(float4*)(out4 + o) = *(const float4*)(emb + o);
  }
}

extern "C" void kernel_launch(void* const* d_in, const int* in_sizes, int n_in,
                              void* d_out, int out_size, void* d_ws, size_t ws_size,
                              hipStream_t stream) {
  (void)in_sizes; (void)n_in; (void)out_size; (void)ws_size;
  const float* x      = (const float*)d_in[0];
  const float* emb    = (const float*)d_in[1];
  const float* ema_cs = (const float*)d_in[2];
  const float* ema_dw = (const float*)d_in[3];
  const int*   counter = (const int*)d_in[4];
  const int*   train   = (const int*)d_in[5];

  float* out = (float*)d_out;
  float* outq    = out + O_Q;
  float* outloss = out + O_LOSS;
  float* outperp = out + O_PERP;
  float* outidx  = out + O_IDX;
  float* out4    = out + O_EMB;

  // workspace carve (bytes)
  char* W = (char*)d_ws;
  unsigned short* Ah   = (unsigned short*)(W);              //  8 MB fp16 x
  unsigned short* Eh   = (unsigned short*)(W + 8388608);    //  4 MB fp16 embT
  float* embT          = (float*)(W + 12582912);            //  8 MB fp32 embT
  float* part1         = (float*)(W + 20971520);            //  4 MB
  float* part2         = (float*)(W + 25165824);            //  4 MB
  int*   partidx       = (int*)(W + 29360128);              //  4 MB
  float* dwT           = (float*)(W + 33554432);            //  8 MB
  unsigned long long* keys = (unsigned long long*)(W + 41943040); // 128 KB
  float* esq           = (float*)(W + 42074112);            // 32 KB
  float* csn           = (float*)(W + 42106880);            // 32 KB
  float* counts        = (float*)(W + 42139648);            // 32 KB
  float* loss_part     = (float*)(W + 42172416);            // 1 KB
  int*   listc         = (int*)(W + 42173440);
  int*   list          = (int*)(W + 42173444);              // 64 KB
  int*   idxw          = (int*)(W + 42238980);              // 64 KB
  int*   rowlist       = (int*)(W + 42304516);              // 64 KB
  int*   basea         = (int*)(W + 42370052);              // 32 KB
  int*   cursor        = (int*)(W + 42402820);              // 32 KB

  k_convert_x<<<4096, 256, 0, stream>>>(x, Ah, esq, counts, loss_part, listc);
  k_convert_e<<<dim3(256, 8), 256, 0, stream>>>(emb, Eh, embT, esq);
  k_dist_mfma<<<dim3(64, 64), 256, 0, stream>>>(Ah, Eh, esq, part1, part2, partidx);
  k_argmin2<<<4096, 256, 0, stream>>>(part1, part2, partidx, idxw, listc, list, keys);
  k_rescore<<<dim3(256, 8), 256, 0, stream>>>(x, emb, listc, list, keys);
  k_index<<<64, 256, 0, stream>>>(idxw, keys, counts);
  k_prefix<<<1, 256, 0, stream>>>(counts, ema_cs, counter, csn, outperp, basea, cursor);
  k_gather<<<4096, 256, 0, stream>>>(x, embT, idxw, train, outq, outidx, rowlist, cursor, loss_part);
  k_dw<<<8192, 64, 0, stream>>>(x, basea, counts, rowlist, train, dwT);
  k_final<<<dim3(256, 8), 256, 0, stream>>>(dwT, ema_dw, emb, csn, counter, train, loss_part, outloss, out4);
}